// Round 13
// baseline (246.469 us; speedup 1.0000x reference)
//
#include <hip/hip_runtime.h>
#include <hip/hip_bf16.h>

#define B_ 32
#define T_ 40
#define P_ 256
#define V_ 4096
#define D_ 256
#define DINO_ 384
#define H_ 4
#define L_ 2
#define HD_ 64
#define DFF_ 1024
#define EPS_ 1e-5f

typedef __bf16 bf16;
typedef __bf16 bf16x8 __attribute__((ext_vector_type(8)));
typedef float f32x4 __attribute__((ext_vector_type(4)));

// bf16 arena holds ONLY fus_w1 (re-read 256x by pproj); other weights are
// staged straight from fp32 by the GEMMs (read-once).
#define FUS_ELEMS 163840     // 640*256
#define FUS_BLOCKS 80        // /2048
#define PAT_BLOCKS 1536      // 32*256*384 / 2048
#define PREP_UNITS 2960      // 1280 embed + 64 transpose + 80 fus + 1536 pat

__device__ __forceinline__ bf16x8 cvt8(const float* p) {
  float4 f0 = *(const float4*)p;
  float4 f1 = *(const float4*)(p + 4);
  bf16x8 v;
  v[0] = (bf16)f0.x; v[1] = (bf16)f0.y; v[2] = (bf16)f0.z; v[3] = (bf16)f0.w;
  v[4] = (bf16)f1.x; v[5] = (bf16)f1.y; v[6] = (bf16)f1.z; v[7] = (bf16)f1.w;
  return v;
}

// ---- shared-memory shapes --------------------------------------------------
// Double-buffered GEMM LDS: 2x(As+Ws) = 18432 B -> still 8 blocks/CU
// (wave-capped), but 1 barrier per K-chunk instead of 2.
struct GemmSM  { bf16 As[2 * 32 * 72]; bf16 Ws[2 * 32 * 72]; };  // 18432 B
struct CprojSM { bf16 As[32 * 264]; bf16 Ws[2 * 32 * 72]; };     // 26112 B
struct AttnSM  { float q[20][65]; float k[40][65]; float v[40][65]; float s[20][41]; };  // 29280 B
struct PrepSM  { float tile[32][33]; };                    //  4224 B
struct FinalSM { float2 cws[4][D_]; };                     //  8192 B

struct Params {
  const float* patches; const int* tokens; const float* tok_emb; const float* pos_emb;
  const float* qkv_w; const float* qkv_b; const float* out_w; const float* out_b;
  const float* ln1_s; const float* ln1_b; const float* w1; const float* b1;
  const float* w2; const float* b2; const float* ln2_s; const float* ln2_b;
  const float* fus_w1; const float* fus_b1; const float* fus_w2; const float* fus_b2;
  const float* cls_w; const float* cls_b; float* out;
  float* x; float* qkvbuf; float* attbuf; float* s; float* pprojT; float* cw;
  bf16* wb; bf16* w2Tb; bf16* patb; bf16* hb;
};

// ---- 32x32 MFMA GEMM tile, double-buffered (1 barrier per K-chunk) --------
// Safety: at iter c we write buf[(c+1)&1], which iter c-1's MFMA read; the
// barrier at the end of iter c-1 orders reads-before-writes. Iter c's MFMA
// reads buf[c&1], staged before the previous barrier.
template <int ABF16, int WF32, int OBF16, int RELU, int RESID, int GATH, int CW>
__device__ __forceinline__ void tile_gemm(
    bf16* As, bf16* Ws, const void* Av, const void* Wv, const float* bias,
    const float* resid, const int* tokens, void* outv, int K, int lda,
    int ldw, int ldc, int bm, int bn) {
  const int tid = threadIdx.x;
  const int lane = tid & 63;
  const int wv = tid >> 6;
  const int mi = wv & 1, ni = wv >> 1;
  const int col = lane & 15, quad = lane >> 4;
  const int srow = tid >> 3, kc = (tid & 7) * 8;
  const float* Af = (const float*)Av;
  const bf16* Ab = (const bf16*)Av;
  const float* Ag = GATH ? (Af + (long)tokens[bm + srow] * D_) : nullptr;
  const float* Wpf = (const float*)Wv + (long)(bn + srow) * ldw + kc;
  const bf16* Wpb = (const bf16*)Wv + (long)(bn + srow) * ldw + kc;

  auto stage = [&](int kk, int buf) {
    bf16* Ad = As + buf * (32 * 72);
    bf16* Wd = Ws + buf * (32 * 72);
    if (GATH)
      *(bf16x8*)&Ad[srow * 72 + kc] = cvt8(Ag + kk + kc);
    else if (ABF16)
      *(bf16x8*)&Ad[srow * 72 + kc] = *(const bf16x8*)(Ab + (long)(bm + srow) * lda + kk + kc);
    else
      *(bf16x8*)&Ad[srow * 72 + kc] = cvt8(Af + (long)(bm + srow) * lda + kk + kc);
    if (WF32)
      *(bf16x8*)&Wd[srow * 72 + kc] = cvt8(Wpf + kk);
    else
      *(bf16x8*)&Wd[srow * 72 + kc] = *(const bf16x8*)(Wpb + kk);
  };

  f32x4 acc = {0.f, 0.f, 0.f, 0.f};
  const int NC = K >> 6;
  stage(0, 0);
  __syncthreads();
  for (int c = 0; c < NC; ++c) {
    if (c + 1 < NC) stage((c + 1) << 6, (c + 1) & 1);
    const bf16* Ac = As + (c & 1) * (32 * 72);
    const bf16* Wc = Ws + (c & 1) * (32 * 72);
#pragma unroll
    for (int ki = 0; ki < 2; ++ki) {
      bf16x8 afr = *(const bf16x8*)&Ac[(mi * 16 + col) * 72 + ki * 32 + quad * 8];
      bf16x8 bfr = *(const bf16x8*)&Wc[(ni * 16 + col) * 72 + ki * 32 + quad * 8];
      acc = __builtin_amdgcn_mfma_f32_16x16x32_bf16(afr, bfr, acc, 0, 0, 0);
    }
    __syncthreads();
  }
  const int n = bn + ni * 16 + col;
  float bv = bias ? bias[n] : 0.0f;
#pragma unroll
  for (int r = 0; r < 4; ++r) {
    int m = bm + mi * 16 + quad * 4 + r;
    float val = acc[r] + bv;
    if (RESID) val += resid[(long)m * D_ + n];
    if (RELU) val = fmaxf(val, 0.0f);
    if (CW == 1) ((float*)outv)[(long)m * (2 * D_) + n * 2] = val;
    else if (CW == 2) ((float*)outv)[(long)m * (2 * D_) + n * 2 + 1] = val;
    else if (OBF16) ((bf16*)outv)[(long)m * ldc + n] = (bf16)val;
    else ((float*)outv)[(long)m * ldc + n] = val;
  }
}

// ---- stage workers ---------------------------------------------------------
__device__ __forceinline__ void do_prep(PrepSM& ps, const Params& P, int u) {
  int tid = threadIdx.x;
  if (u < 1280) {
    P.x[u * D_ + tid] = P.tok_emb[(long)P.tokens[u] * D_ + tid] + P.pos_emb[(u % T_) * D_ + tid];
  } else if (u < 1344) {
    int tt = u - 1280;
    int bx = (tt & 7) * 32, by = (tt >> 3) * 32;
    int tx = tid & 31, ty = tid >> 5;  // 32 x 8
#pragma unroll
    for (int i = 0; i < 32; i += 8) ps.tile[ty + i][tx] = P.fus_w2[(by + ty + i) * D_ + bx + tx];
    __syncthreads();
#pragma unroll
    for (int i = 0; i < 32; i += 8)
      P.w2Tb[(bx + ty + i) * D_ + by + tx] = (bf16)ps.tile[tx][ty + i];
  } else if (u < 1344 + FUS_BLOCKS) {
    long f = (long)(u - 1344) * 2048 + tid * 8;
    *(bf16x8*)&P.wb[f] = cvt8(P.fus_w1 + f);
  } else {
    long f = (long)(u - 1344 - FUS_BLOCKS) * 2048 + tid * 8;
    *(bf16x8*)&P.patb[f] = cvt8(P.patches + f);
  }
}

__device__ __forceinline__ void do_qkv(GemmSM& g, const Params& P, int l, int u) {
  tile_gemm<0, 1, 0, 0, 0, 0, 0>(g.As, g.Ws, P.x, P.qkv_w + (long)l * 3 * D_ * D_,
                                 P.qkv_b + l * 3 * D_, nullptr, nullptr, P.qkvbuf,
                                 256, D_, D_, 3 * D_, (u / 24) * 32, (u % 24) * 32);
}
__device__ __forceinline__ void do_proj(GemmSM& g, const Params& P, int l, int u) {
  tile_gemm<0, 1, 0, 0, 1, 0, 0>(g.As, g.Ws, P.attbuf, P.out_w + (long)l * D_ * D_,
                                 P.out_b + l * D_, P.x, nullptr, P.s,
                                 256, D_, D_, D_, (u / 8) * 32, (u % 8) * 32);
}
__device__ __forceinline__ void do_w1(GemmSM& g, const Params& P, int l, int u) {
  tile_gemm<0, 1, 1, 1, 0, 0, 0>(g.As, g.Ws, P.x, P.w1 + (long)l * DFF_ * D_,
                                 P.b1 + l * DFF_, nullptr, nullptr, P.hb,
                                 256, D_, D_, DFF_, (u / 32) * 32, (u % 32) * 32);
}
__device__ __forceinline__ void do_w2(GemmSM& g, const Params& P, int l, int u) {
  tile_gemm<1, 1, 0, 0, 1, 0, 0>(g.As, g.Ws, P.hb, P.w2 + (long)l * D_ * DFF_,
                                 P.b2 + l * D_, P.x, nullptr, P.s,
                                 DFF_, DFF_, DFF_, D_, (u / 8) * 32, (u % 8) * 32);
}
__device__ __forceinline__ void do_pproj(GemmSM& g, const Params& P, int t) {
  int bn = (t & 7) * 32; int y = t >> 3; int bb = y >> 3; int bm = (y & 7) * 32;
  tile_gemm<1, 0, 0, 0, 0, 0, 0>(g.As, g.Ws, P.wb, P.patb + (long)bb * P_ * DINO_,
                                 nullptr, nullptr, nullptr, P.pprojT + (long)bb * D_ * P_,
                                 384, 640, DINO_, P_, bm, bn);
}
__device__ __forceinline__ void do_weff(GemmSM& g, const Params& P, int t) {
  tile_gemm<0, 0, 0, 0, 0, 1, 2>(g.As, g.Ws, P.cls_w, P.w2Tb, nullptr, nullptr,
                                 P.tokens, P.cw, 256, D_, D_, D_,
                                 (t / 8) * 32, (t % 8) * 32);
}

__device__ __forceinline__ void do_attn(AttnSM& A, const Params& P, int u) {
  int h = u & 3, b = (u >> 2) & 31, zq = u >> 7;
  int r0 = zq * 20;
  int tid = threadIdx.x;
  int lane = tid & 63, wv = tid >> 6;
  const float* qkv = P.qkvbuf;
  for (int idx = tid; idx < T_ * HD_; idx += 256) {
    int t = idx >> 6, d = idx & 63;
    long base = (long)(b * T_ + t) * (3 * D_) + h * HD_ + d;
    A.k[t][d] = qkv[base + D_];
    A.v[t][d] = qkv[base + 2 * D_];
    if (t < 20) A.q[t][d] = qkv[(long)(b * T_ + r0 + t) * (3 * D_) + h * HD_ + d];
  }
  __syncthreads();
  for (int idx = tid; idx < 20 * T_; idx += 256) {
    int i = idx / T_, j = idx - i * T_;
    if (j <= r0 + i) {
      float acc = 0.f;
#pragma unroll
      for (int d = 0; d < HD_; ++d) acc += A.q[i][d] * A.k[j][d];
      A.s[i][j] = acc * 0.125f;
    }
  }
  __syncthreads();
  for (int rr = wv; rr < 20; rr += 4) {
    int hi = r0 + rr;
    float val = (lane <= hi) ? A.s[rr][lane] : -1e30f;
    float mx = val;
#pragma unroll
    for (int mk = 1; mk < 64; mk <<= 1) mx = fmaxf(mx, __shfl_xor(mx, mk));
    float e = (lane <= hi)
                  ? __builtin_amdgcn_exp2f((val - mx) * 1.4426950408889634f)
                  : 0.f;
    float sum = e;
#pragma unroll
    for (int mk = 1; mk < 64; mk <<= 1) sum += __shfl_xor(sum, mk);
    float inv = __builtin_amdgcn_rcpf(sum);
    if (lane < T_) A.s[rr][lane] = e * inv;
  }
  __syncthreads();
  for (int idx = tid; idx < 20 * HD_; idx += 256) {
    int i = idx >> 6, d = idx & 63;
    int hi = r0 + i;
    float acc = 0.f;
    for (int j = 0; j <= hi; ++j) acc += A.s[i][j] * A.v[j][d];
    P.attbuf[(long)(b * T_ + hi) * D_ + h * HD_ + d] = acc;
  }
}

__device__ __forceinline__ void do_cproj(CprojSM& c, const Params& P, int bm, int bn) {
  const int tid = threadIdx.x;
  const int lane = tid & 63;
  const int wv = tid >> 6;
  const int mi = wv & 1, ni = wv >> 1;
  const int col = lane & 15, quad = lane >> 4;
  const int srow = tid >> 3, kc = (tid & 7) * 8;
  const int gm = bm + srow;
  f32x4 acc = {0.f, 0.f, 0.f, 0.f};
  const int cg = (tid & 7) * 32;
  const int t = gm % T_;
  if (t == 0) {
    bf16x8 z8 = {};
#pragma unroll
    for (int i = 0; i < 4; ++i) *(bf16x8*)&c.As[srow * 264 + cg + i * 8] = z8;
  } else {
    const float* sp = P.s + (long)(gm - 1) * D_ + cg;
    float v[32];
    float sum = 0.f, ss = 0.f;
#pragma unroll
    for (int i = 0; i < 8; ++i) {
      float4 f = *(const float4*)(sp + i * 4);
      v[i*4] = f.x; v[i*4+1] = f.y; v[i*4+2] = f.z; v[i*4+3] = f.w;
      sum += f.x + f.y + f.z + f.w;
      ss += f.x*f.x + f.y*f.y + f.z*f.z + f.w*f.w;
    }
#pragma unroll
    for (int mk = 1; mk < 8; mk <<= 1) {
      sum += __shfl_xor(sum, mk);
      ss += __shfl_xor(ss, mk);
    }
    float mean = sum * (1.0f / D_);
    float inv = rsqrtf(ss * (1.0f / D_) - mean * mean + EPS_);
    const float* lng = P.ln2_s + D_;
    const float* lnb = P.ln2_b + D_;
#pragma unroll
    for (int i = 0; i < 8; ++i) {
      float4 g4 = *(const float4*)(lng + cg + i * 4);
      float4 b4 = *(const float4*)(lnb + cg + i * 4);
      c.As[srow*264 + cg + i*4]     = (bf16)((v[i*4]   - mean) * inv * g4.x + b4.x);
      c.As[srow*264 + cg + i*4 + 1] = (bf16)((v[i*4+1] - mean) * inv * g4.y + b4.y);
      c.As[srow*264 + cg + i*4 + 2] = (bf16)((v[i*4+2] - mean) * inv * g4.z + b4.z);
      c.As[srow*264 + cg + i*4 + 3] = (bf16)((v[i*4+3] - mean) * inv * g4.w + b4.w);
    }
  }
  // W double-buffered: 1 barrier per chunk
  const bf16* Wp = P.wb + 384 + (long)(bn + srow) * 640 + kc;
  *(bf16x8*)&c.Ws[srow * 72 + kc] = *(const bf16x8*)(Wp + 0);
  __syncthreads();
  for (int cc = 0; cc < 4; ++cc) {
    if (cc + 1 < 4)
      *(bf16x8*)&c.Ws[((cc + 1) & 1) * (32 * 72) + srow * 72 + kc] =
          *(const bf16x8*)(Wp + ((cc + 1) << 6));
    const bf16* Wc = c.Ws + (cc & 1) * (32 * 72);
    const int kk = cc << 6;
#pragma unroll
    for (int ki = 0; ki < 2; ++ki) {
      bf16x8 afr = *(const bf16x8*)&c.As[(mi*16 + col) * 264 + kk + ki*32 + quad*8];
      bf16x8 bfr = *(const bf16x8*)&Wc[(ni*16 + col) * 72 + ki*32 + quad*8];
      acc = __builtin_amdgcn_mfma_f32_16x16x32_bf16(afr, bfr, acc, 0, 0, 0);
    }
    __syncthreads();
  }
  const int n = bn + ni * 16 + col;
  float bv = P.fus_b1[n];
#pragma unroll
  for (int r = 0; r < 4; ++r) {
    int m = bm + mi * 16 + quad * 4 + r;
    P.cw[(long)m * (2 * D_) + n * 2] = acc[r] + bv;
  }
}

__device__ __forceinline__ void do_final(FinalSM& F, const Params& P, int u) {
  int tid = threadIdx.x;
  int lane = tid & 63, wv = tid >> 6;
  int px = u & 3, rest = u >> 2;
  int ty = rest % 10, b = rest / 10;
  int p = px * 64 + lane;
  int t = ty * 4 + wv;
  int mbase = b * T_ + ty * 4;
  for (int idx = tid; idx < 4 * D_; idx += 256) {
    int tt = idx >> 8, e = idx & 255;
    F.cws[tt][e] = ((const float2*)P.cw)[(long)(mbase + tt) * D_ + e];
  }
  __syncthreads();

  int m = b * T_ + t;
  int tok = P.tokens[m];
  const float* cr = P.cls_w + (long)tok * D_;
  float bacc = 0.f;
#pragma unroll
  for (int i = 0; i < 4; ++i) bacc += cr[lane + i * 64] * P.fus_b2[lane + i * 64];
#pragma unroll
  for (int mk = 1; mk < 64; mk <<= 1) bacc += __shfl_xor(bacc, mk);
  float beff = bacc + P.cls_b[tok];

  const float* ppb = P.pprojT + (long)b * (D_ * P_);  // [e][p]
  float acc = 0.f;
#pragma unroll 8
  for (int e = 0; e < D_; ++e) {
    float pp = ppb[e * P_ + p];
    float2 c = F.cws[wv][e];
    float x = pp + c.x;
    float ex = __builtin_amdgcn_exp2f(-2.4554248f * x);  // -1.702*log2e
    float r = __builtin_amdgcn_rcpf(1.0f + ex);
    acc = fmaf(x * r, c.y, acc);
  }
  float logit = acc + beff;
  float es = __builtin_amdgcn_exp2f(-1.4426950408889634f * logit);
  P.out[(long)(b * P_ + p) * T_ + t] = __builtin_amdgcn_rcpf(1.0f + es);
}

// ---- launch wrappers -------------------------------------------------------
__global__ __launch_bounds__(256) void prep_k(Params P) {
  __shared__ PrepSM ps; do_prep(ps, P, blockIdx.x);
}
__global__ __launch_bounds__(256) void qkv_k(Params P, int l) {
  __shared__ GemmSM g; do_qkv(g, P, l, blockIdx.x);
}
// attn(l=0) + pproj + weff riders (riders depend only on prep)
__global__ __launch_bounds__(256) void apw_k(Params P) {
  __shared__ union __align__(16) { AttnSM a; GemmSM g; } sm;
  int bid = blockIdx.x;
  if (bid < 256) do_attn(sm.a, P, bid);
  else if (bid < 2304) do_pproj(sm.g, P, bid - 256);
  else do_weff(sm.g, P, bid - 2304);
}
__global__ __launch_bounds__(256) void attn_k(Params P) {
  __shared__ AttnSM a; do_attn(a, P, blockIdx.x);
}
__global__ __launch_bounds__(256) void proj_k(Params P, int l) {
  __shared__ GemmSM g; do_proj(g, P, l, blockIdx.x);
}
__global__ __launch_bounds__(256) void ln_k(const float* __restrict__ s,
                                            float* __restrict__ xout,
                                            const float* __restrict__ g,
                                            const float* __restrict__ be) {
  int wv = threadIdx.x >> 6, lane = threadIdx.x & 63;
  int m = blockIdx.x * 4 + wv;
  float4 v = *(const float4*)(s + (long)m * D_ + lane * 4);
  float sum = v.x + v.y + v.z + v.w;
  float ss = v.x * v.x + v.y * v.y + v.z * v.z + v.w * v.w;
#pragma unroll
  for (int mk = 1; mk < 64; mk <<= 1) {
    sum += __shfl_xor(sum, mk);
    ss += __shfl_xor(ss, mk);
  }
  float mean = sum * (1.0f / D_);
  float inv = rsqrtf(ss * (1.0f / D_) - mean * mean + EPS_);
  float4 g4 = *(const float4*)(g + lane * 4);
  float4 b4 = *(const float4*)(be + lane * 4);
  float4 o;
  o.x = (v.x - mean) * inv * g4.x + b4.x;
  o.y = (v.y - mean) * inv * g4.y + b4.y;
  o.z = (v.z - mean) * inv * g4.z + b4.z;
  o.w = (v.w - mean) * inv * g4.w + b4.w;
  *(float4*)(xout + (long)m * D_ + lane * 4) = o;
}
__global__ __launch_bounds__(256) void w1_k(Params P, int l) {
  __shared__ GemmSM g; do_w1(g, P, l, blockIdx.x);
}
__global__ __launch_bounds__(256) void w2_k(Params P, int l) {
  __shared__ GemmSM g; do_w2(g, P, l, blockIdx.x);
}
__global__ __launch_bounds__(256) void cproj_k(Params P) {
  __shared__ CprojSM c; do_cproj(c, P, (blockIdx.x >> 3) * 32, (blockIdx.x & 7) * 32);
}
__global__ __launch_bounds__(256) void final_k(Params P) {
  __shared__ FinalSM f; do_final(f, P, blockIdx.x);
}

extern "C" void kernel_launch(void* const* d_in, const int* in_sizes, int n_in, void* d_out,
                              int out_size, void* d_ws, size_t ws_size, hipStream_t stream) {
  Params P;
  P.patches = (const float*)d_in[0];
  P.tokens = (const int*)d_in[1];
  P.tok_emb = (const float*)d_in[2];
  P.pos_emb = (const float*)d_in[3];
  P.qkv_w = (const float*)d_in[4];
  P.qkv_b = (const float*)d_in[5];
  P.out_w = (const float*)d_in[6];
  P.out_b = (const float*)d_in[7];
  P.ln1_s = (const float*)d_in[8];
  P.ln1_b = (const float*)d_in[9];
  P.w1 = (const float*)d_in[10];
  P.b1 = (const float*)d_in[11];
  P.w2 = (const float*)d_in[12];
  P.b2 = (const float*)d_in[13];
  P.ln2_s = (const float*)d_in[14];
  P.ln2_b = (const float*)d_in[15];
  P.fus_w1 = (const float*)d_in[16];
  P.fus_b1 = (const float*)d_in[17];
  P.fus_w2 = (const float*)d_in[18];
  P.fus_b2 = (const float*)d_in[19];
  P.cls_w = (const float*)d_in[20];
  P.cls_b = (const float*)d_in[21];
  P.out = (float*)d_out;

  const int MT = B_ * T_;  // 1280
  P.x = (float*)d_ws;                          // 1280*256
  P.qkvbuf = P.x + MT * D_;                    // 1280*768
  P.attbuf = P.qkvbuf + MT * 3 * D_;           // 1280*256
  P.s = P.attbuf + MT * D_;                    // 1280*256
  P.pprojT = P.s + MT * D_;                    // 32*256*256 [b][e][p]
  P.cw = P.pprojT + (long)B_ * D_ * P_;        // 1280*512 {cproj,weff}
  P.wb = (bf16*)(P.cw + MT * D_ * 2);          // bf16 fus_w1 arena
  P.w2Tb = P.wb + FUS_ELEMS;                   // 256*256
  P.patb = P.w2Tb + D_ * D_;                   // 32*256*384
  P.hb = P.patb + (long)B_ * P_ * DINO_;       // 1280*1024 bf16

  // 1. prep: embed->x, fus_w2 transpose, fus_w1->bf16, patches->bf16
  prep_k<<<PREP_UNITS, 256, 0, stream>>>(P);
  // 2. qkv(l=0), W staged from fp32
  qkv_k<<<960, 256, 0, stream>>>(P, 0);
  // 3. attn(l=0) + pproj + weff riders (fill idle CUs; tail shrinks to cproj)
  apw_k<<<2624, 256, 0, stream>>>(P);
  // 4. proj(l=0) + resid
  proj_k<<<320, 256, 0, stream>>>(P, 0);
  // 5. x = LN1(s)
  ln_k<<<320, 256, 0, stream>>>(P.s, P.x, P.ln1_s, P.ln1_b);
  // 6. hb = relu(x @ w1^T + b1)
  w1_k<<<1280, 256, 0, stream>>>(P, 0);
  // 7. s = hb @ w2^T + b2 + x
  w2_k<<<320, 256, 0, stream>>>(P, 0);
  // 8. x = LN2(s)
  ln_k<<<320, 256, 0, stream>>>(P.s, P.x, P.ln2_s, P.ln2_b);
  // 9-14. layer 1
  qkv_k<<<960, 256, 0, stream>>>(P, 1);
  attn_k<<<256, 256, 0, stream>>>(P);
  proj_k<<<320, 256, 0, stream>>>(P, 1);
  ln_k<<<320, 256, 0, stream>>>(P.s, P.x, P.ln1_s + D_, P.ln1_b + D_);
  w1_k<<<1280, 256, 0, stream>>>(P, 1);
  w2_k<<<320, 256, 0, stream>>>(P, 1);
  // 15. cproj: shifted LN2(l=1) folded -> cw even (+fus_b1)
  cproj_k<<<320, 256, 0, stream>>>(P);
  // 16. final
  final_k<<<1280, 256, 0, stream>>>(P);
}

// Round 14
// 244.234 us; speedup vs baseline: 1.0091x; 1.0091x over previous
//
#include <hip/hip_runtime.h>
#include <hip/hip_bf16.h>

#define B_ 32
#define T_ 40
#define P_ 256
#define V_ 4096
#define D_ 256
#define DINO_ 384
#define H_ 4
#define L_ 2
#define HD_ 64
#define DFF_ 1024
#define EPS_ 1e-5f

typedef __bf16 bf16;
typedef __bf16 bf16x8 __attribute__((ext_vector_type(8)));
typedef float f32x4 __attribute__((ext_vector_type(4)));

// bf16 arena holds ONLY fus_w1 (re-read 256x by pproj); other weights are
// staged straight from fp32 by the GEMMs (read-once).
#define FUS_ELEMS 163840     // 640*256
#define FUS_BLOCKS 20        // /8192
#define PAT_BLOCKS 384       // 32*256*384 / 8192
#define PREP_UNITS 788       // 320 embed + 64 transpose + 20 fus + 384 pat

__device__ __forceinline__ bf16x8 cvt8(const float* p) {
  float4 f0 = *(const float4*)p;
  float4 f1 = *(const float4*)(p + 4);
  bf16x8 v;
  v[0] = (bf16)f0.x; v[1] = (bf16)f0.y; v[2] = (bf16)f0.z; v[3] = (bf16)f0.w;
  v[4] = (bf16)f1.x; v[5] = (bf16)f1.y; v[6] = (bf16)f1.z; v[7] = (bf16)f1.w;
  return v;
}

// ---- shared-memory shapes --------------------------------------------------
// Double-buffered GEMM LDS: 2x(As+Ws) = 18432 B -> still 8 blocks/CU
// (wave-capped), but 1 barrier per K-chunk instead of 2.
struct GemmSM  { bf16 As[2 * 32 * 72]; bf16 Ws[2 * 32 * 72]; };  // 18432 B
struct CprojSM { bf16 As[32 * 264]; bf16 Ws[2 * 32 * 72]; };     // 26112 B
struct AttnSM  { float q[20][65]; float k[40][65]; float v[40][65]; float s[20][41]; };  // 29280 B
struct PrepSM  { float tile[32][33]; };                    //  4224 B
struct FinalSM { float2 cws[4][D_]; };                     //  8192 B

struct Params {
  const float* patches; const int* tokens; const float* tok_emb; const float* pos_emb;
  const float* qkv_w; const float* qkv_b; const float* out_w; const float* out_b;
  const float* ln1_s; const float* ln1_b; const float* w1; const float* b1;
  const float* w2; const float* b2; const float* ln2_s; const float* ln2_b;
  const float* fus_w1; const float* fus_b1; const float* fus_w2; const float* fus_b2;
  const float* cls_w; const float* cls_b; float* out;
  float* x; float* qkvbuf; float* attbuf; float* s; float* pprojT; float* cw;
  bf16* wb; bf16* w2Tb; bf16* patb; bf16* hb;
};

// ---- 32x32 MFMA GEMM tile, double-buffered (1 barrier per K-chunk) --------
// Safety: at iter c we write buf[(c+1)&1], which iter c-1's MFMA read; the
// barrier at the end of iter c-1 orders reads-before-writes. Iter c's MFMA
// reads buf[c&1], staged before the previous barrier.
template <int ABF16, int WF32, int OBF16, int RELU, int RESID, int GATH, int CW>
__device__ __forceinline__ void tile_gemm(
    bf16* As, bf16* Ws, const void* Av, const void* Wv, const float* bias,
    const float* resid, const int* tokens, void* outv, int K, int lda,
    int ldw, int ldc, int bm, int bn) {
  const int tid = threadIdx.x;
  const int lane = tid & 63;
  const int wv = tid >> 6;
  const int mi = wv & 1, ni = wv >> 1;
  const int col = lane & 15, quad = lane >> 4;
  const int srow = tid >> 3, kc = (tid & 7) * 8;
  const float* Af = (const float*)Av;
  const bf16* Ab = (const bf16*)Av;
  const float* Ag = GATH ? (Af + (long)tokens[bm + srow] * D_) : nullptr;
  const float* Wpf = (const float*)Wv + (long)(bn + srow) * ldw + kc;
  const bf16* Wpb = (const bf16*)Wv + (long)(bn + srow) * ldw + kc;

  auto stage = [&](int kk, int buf) {
    bf16* Ad = As + buf * (32 * 72);
    bf16* Wd = Ws + buf * (32 * 72);
    if (GATH)
      *(bf16x8*)&Ad[srow * 72 + kc] = cvt8(Ag + kk + kc);
    else if (ABF16)
      *(bf16x8*)&Ad[srow * 72 + kc] = *(const bf16x8*)(Ab + (long)(bm + srow) * lda + kk + kc);
    else
      *(bf16x8*)&Ad[srow * 72 + kc] = cvt8(Af + (long)(bm + srow) * lda + kk + kc);
    if (WF32)
      *(bf16x8*)&Wd[srow * 72 + kc] = cvt8(Wpf + kk);
    else
      *(bf16x8*)&Wd[srow * 72 + kc] = *(const bf16x8*)(Wpb + kk);
  };

  f32x4 acc = {0.f, 0.f, 0.f, 0.f};
  const int NC = K >> 6;
  stage(0, 0);
  __syncthreads();
  for (int c = 0; c < NC; ++c) {
    if (c + 1 < NC) stage((c + 1) << 6, (c + 1) & 1);
    const bf16* Ac = As + (c & 1) * (32 * 72);
    const bf16* Wc = Ws + (c & 1) * (32 * 72);
#pragma unroll
    for (int ki = 0; ki < 2; ++ki) {
      bf16x8 afr = *(const bf16x8*)&Ac[(mi * 16 + col) * 72 + ki * 32 + quad * 8];
      bf16x8 bfr = *(const bf16x8*)&Wc[(ni * 16 + col) * 72 + ki * 32 + quad * 8];
      acc = __builtin_amdgcn_mfma_f32_16x16x32_bf16(afr, bfr, acc, 0, 0, 0);
    }
    __syncthreads();
  }
  const int n = bn + ni * 16 + col;
  float bv = bias ? bias[n] : 0.0f;
#pragma unroll
  for (int r = 0; r < 4; ++r) {
    int m = bm + mi * 16 + quad * 4 + r;
    float val = acc[r] + bv;
    if (RESID) val += resid[(long)m * D_ + n];
    if (RELU) val = fmaxf(val, 0.0f);
    if (CW == 1) ((float*)outv)[(long)m * (2 * D_) + n * 2] = val;
    else if (CW == 2) ((float*)outv)[(long)m * (2 * D_) + n * 2 + 1] = val;
    else if (OBF16) ((bf16*)outv)[(long)m * ldc + n] = (bf16)val;
    else ((float*)outv)[(long)m * ldc + n] = val;
  }
}

// ---- stage workers ---------------------------------------------------------
// prep, single-pass sized: 320 embed (4 rows/blk) + 64 transpose +
// 20 fus-conv + 384 patch-conv (32 elems/thread)
__device__ __forceinline__ void do_prep(PrepSM& ps, const Params& P, int u) {
  int tid = threadIdx.x;
  if (u < 320) {
    int r = tid >> 6, lane = tid & 63;
    int m = u * 4 + r;
    long eb = (long)P.tokens[m] * D_ + lane * 4;
    long pb = (long)(m % T_) * D_ + lane * 4;
    float4 e = *(const float4*)(P.tok_emb + eb);
    float4 p = *(const float4*)(P.pos_emb + pb);
    float4 o; o.x = e.x + p.x; o.y = e.y + p.y; o.z = e.z + p.z; o.w = e.w + p.w;
    *(float4*)(P.x + (long)m * D_ + lane * 4) = o;
  } else if (u < 384) {
    int tt = u - 320;
    int bx = (tt & 7) * 32, by = (tt >> 3) * 32;
    int tx = tid & 31, ty = tid >> 5;  // 32 x 8
#pragma unroll
    for (int i = 0; i < 32; i += 8) ps.tile[ty + i][tx] = P.fus_w2[(by + ty + i) * D_ + bx + tx];
    __syncthreads();
#pragma unroll
    for (int i = 0; i < 32; i += 8)
      P.w2Tb[(bx + ty + i) * D_ + by + tx] = (bf16)ps.tile[tx][ty + i];
  } else if (u < 384 + FUS_BLOCKS) {
    long base = (long)(u - 384) * 8192;
#pragma unroll
    for (int j = 0; j < 4; ++j) {
      long f = base + j * 2048 + tid * 8;
      *(bf16x8*)&P.wb[f] = cvt8(P.fus_w1 + f);
    }
  } else {
    long base = (long)(u - 384 - FUS_BLOCKS) * 8192;
#pragma unroll
    for (int j = 0; j < 4; ++j) {
      long f = base + j * 2048 + tid * 8;
      *(bf16x8*)&P.patb[f] = cvt8(P.patches + f);
    }
  }
}

__device__ __forceinline__ void do_qkv(GemmSM& g, const Params& P, int l, int u) {
  tile_gemm<0, 1, 0, 0, 0, 0, 0>(g.As, g.Ws, P.x, P.qkv_w + (long)l * 3 * D_ * D_,
                                 P.qkv_b + l * 3 * D_, nullptr, nullptr, P.qkvbuf,
                                 256, D_, D_, 3 * D_, (u / 24) * 32, (u % 24) * 32);
}
__device__ __forceinline__ void do_proj(GemmSM& g, const Params& P, int l, int u) {
  tile_gemm<0, 1, 0, 0, 1, 0, 0>(g.As, g.Ws, P.attbuf, P.out_w + (long)l * D_ * D_,
                                 P.out_b + l * D_, P.x, nullptr, P.s,
                                 256, D_, D_, D_, (u / 8) * 32, (u % 8) * 32);
}
__device__ __forceinline__ void do_w1(GemmSM& g, const Params& P, int l, int u) {
  tile_gemm<0, 1, 1, 1, 0, 0, 0>(g.As, g.Ws, P.x, P.w1 + (long)l * DFF_ * D_,
                                 P.b1 + l * DFF_, nullptr, nullptr, P.hb,
                                 256, D_, D_, DFF_, (u / 32) * 32, (u % 32) * 32);
}
__device__ __forceinline__ void do_w2(GemmSM& g, const Params& P, int l, int u) {
  tile_gemm<1, 1, 0, 0, 1, 0, 0>(g.As, g.Ws, P.hb, P.w2 + (long)l * D_ * DFF_,
                                 P.b2 + l * D_, P.x, nullptr, P.s,
                                 DFF_, DFF_, DFF_, D_, (u / 8) * 32, (u % 8) * 32);
}
__device__ __forceinline__ void do_pproj(GemmSM& g, const Params& P, int t) {
  int bn = (t & 7) * 32; int y = t >> 3; int bb = y >> 3; int bm = (y & 7) * 32;
  tile_gemm<1, 0, 0, 0, 0, 0, 0>(g.As, g.Ws, P.wb, P.patb + (long)bb * P_ * DINO_,
                                 nullptr, nullptr, nullptr, P.pprojT + (long)bb * D_ * P_,
                                 384, 640, DINO_, P_, bm, bn);
}
__device__ __forceinline__ void do_weff(GemmSM& g, const Params& P, int t) {
  tile_gemm<0, 0, 0, 0, 0, 1, 2>(g.As, g.Ws, P.cls_w, P.w2Tb, nullptr, nullptr,
                                 P.tokens, P.cw, 256, D_, D_, D_,
                                 (t / 8) * 32, (t % 8) * 32);
}

__device__ __forceinline__ void do_attn(AttnSM& A, const Params& P, int u) {
  int h = u & 3, b = (u >> 2) & 31, zq = u >> 7;
  int r0 = zq * 20;
  int tid = threadIdx.x;
  int lane = tid & 63, wv = tid >> 6;
  const float* qkv = P.qkvbuf;
  for (int idx = tid; idx < T_ * HD_; idx += 256) {
    int t = idx >> 6, d = idx & 63;
    long base = (long)(b * T_ + t) * (3 * D_) + h * HD_ + d;
    A.k[t][d] = qkv[base + D_];
    A.v[t][d] = qkv[base + 2 * D_];
    if (t < 20) A.q[t][d] = qkv[(long)(b * T_ + r0 + t) * (3 * D_) + h * HD_ + d];
  }
  __syncthreads();
  for (int idx = tid; idx < 20 * T_; idx += 256) {
    int i = idx / T_, j = idx - i * T_;
    if (j <= r0 + i) {
      float acc = 0.f;
#pragma unroll
      for (int d = 0; d < HD_; ++d) acc += A.q[i][d] * A.k[j][d];
      A.s[i][j] = acc * 0.125f;
    }
  }
  __syncthreads();
  for (int rr = wv; rr < 20; rr += 4) {
    int hi = r0 + rr;
    float val = (lane <= hi) ? A.s[rr][lane] : -1e30f;
    float mx = val;
#pragma unroll
    for (int mk = 1; mk < 64; mk <<= 1) mx = fmaxf(mx, __shfl_xor(mx, mk));
    float e = (lane <= hi)
                  ? __builtin_amdgcn_exp2f((val - mx) * 1.4426950408889634f)
                  : 0.f;
    float sum = e;
#pragma unroll
    for (int mk = 1; mk < 64; mk <<= 1) sum += __shfl_xor(sum, mk);
    float inv = __builtin_amdgcn_rcpf(sum);
    if (lane < T_) A.s[rr][lane] = e * inv;
  }
  __syncthreads();
  for (int idx = tid; idx < 20 * HD_; idx += 256) {
    int i = idx >> 6, d = idx & 63;
    int hi = r0 + i;
    float acc = 0.f;
    for (int j = 0; j <= hi; ++j) acc += A.s[i][j] * A.v[j][d];
    P.attbuf[(long)(b * T_ + hi) * D_ + h * HD_ + d] = acc;
  }
}

__device__ __forceinline__ void do_cproj(CprojSM& c, const Params& P, int bm, int bn) {
  const int tid = threadIdx.x;
  const int lane = tid & 63;
  const int wv = tid >> 6;
  const int mi = wv & 1, ni = wv >> 1;
  const int col = lane & 15, quad = lane >> 4;
  const int srow = tid >> 3, kc = (tid & 7) * 8;
  const int gm = bm + srow;
  f32x4 acc = {0.f, 0.f, 0.f, 0.f};
  const int cg = (tid & 7) * 32;
  const int t = gm % T_;
  if (t == 0) {
    bf16x8 z8 = {};
#pragma unroll
    for (int i = 0; i < 4; ++i) *(bf16x8*)&c.As[srow * 264 + cg + i * 8] = z8;
  } else {
    const float* sp = P.s + (long)(gm - 1) * D_ + cg;
    float v[32];
    float sum = 0.f, ss = 0.f;
#pragma unroll
    for (int i = 0; i < 8; ++i) {
      float4 f = *(const float4*)(sp + i * 4);
      v[i*4] = f.x; v[i*4+1] = f.y; v[i*4+2] = f.z; v[i*4+3] = f.w;
      sum += f.x + f.y + f.z + f.w;
      ss += f.x*f.x + f.y*f.y + f.z*f.z + f.w*f.w;
    }
#pragma unroll
    for (int mk = 1; mk < 8; mk <<= 1) {
      sum += __shfl_xor(sum, mk);
      ss += __shfl_xor(ss, mk);
    }
    float mean = sum * (1.0f / D_);
    float inv = rsqrtf(ss * (1.0f / D_) - mean * mean + EPS_);
    const float* lng = P.ln2_s + D_;
    const float* lnb = P.ln2_b + D_;
#pragma unroll
    for (int i = 0; i < 8; ++i) {
      float4 g4 = *(const float4*)(lng + cg + i * 4);
      float4 b4 = *(const float4*)(lnb + cg + i * 4);
      c.As[srow*264 + cg + i*4]     = (bf16)((v[i*4]   - mean) * inv * g4.x + b4.x);
      c.As[srow*264 + cg + i*4 + 1] = (bf16)((v[i*4+1] - mean) * inv * g4.y + b4.y);
      c.As[srow*264 + cg + i*4 + 2] = (bf16)((v[i*4+2] - mean) * inv * g4.z + b4.z);
      c.As[srow*264 + cg + i*4 + 3] = (bf16)((v[i*4+3] - mean) * inv * g4.w + b4.w);
    }
  }
  // W double-buffered: 1 barrier per chunk
  const bf16* Wp = P.wb + 384 + (long)(bn + srow) * 640 + kc;
  *(bf16x8*)&c.Ws[srow * 72 + kc] = *(const bf16x8*)(Wp + 0);
  __syncthreads();
  for (int cc = 0; cc < 4; ++cc) {
    if (cc + 1 < 4)
      *(bf16x8*)&c.Ws[((cc + 1) & 1) * (32 * 72) + srow * 72 + kc] =
          *(const bf16x8*)(Wp + ((cc + 1) << 6));
    const bf16* Wc = c.Ws + (cc & 1) * (32 * 72);
    const int kk = cc << 6;
#pragma unroll
    for (int ki = 0; ki < 2; ++ki) {
      bf16x8 afr = *(const bf16x8*)&c.As[(mi*16 + col) * 264 + kk + ki*32 + quad*8];
      bf16x8 bfr = *(const bf16x8*)&Wc[(ni*16 + col) * 72 + ki*32 + quad*8];
      acc = __builtin_amdgcn_mfma_f32_16x16x32_bf16(afr, bfr, acc, 0, 0, 0);
    }
    __syncthreads();
  }
  const int n = bn + ni * 16 + col;
  float bv = P.fus_b1[n];
#pragma unroll
  for (int r = 0; r < 4; ++r) {
    int m = bm + mi * 16 + quad * 4 + r;
    P.cw[(long)m * (2 * D_) + n * 2] = acc[r] + bv;
  }
}

__device__ __forceinline__ void do_final(FinalSM& F, const Params& P, int u) {
  int tid = threadIdx.x;
  int lane = tid & 63, wv = tid >> 6;
  int px = u & 3, rest = u >> 2;
  int ty = rest % 10, b = rest / 10;
  int p = px * 64 + lane;
  int t = ty * 4 + wv;
  int mbase = b * T_ + ty * 4;
  for (int idx = tid; idx < 4 * D_; idx += 256) {
    int tt = idx >> 8, e = idx & 255;
    F.cws[tt][e] = ((const float2*)P.cw)[(long)(mbase + tt) * D_ + e];
  }
  __syncthreads();

  int m = b * T_ + t;
  int tok = P.tokens[m];
  const float* cr = P.cls_w + (long)tok * D_;
  float bacc = 0.f;
#pragma unroll
  for (int i = 0; i < 4; ++i) bacc += cr[lane + i * 64] * P.fus_b2[lane + i * 64];
#pragma unroll
  for (int mk = 1; mk < 64; mk <<= 1) bacc += __shfl_xor(bacc, mk);
  float beff = bacc + P.cls_b[tok];

  const float* ppb = P.pprojT + (long)b * (D_ * P_);  // [e][p]
  float acc = 0.f;
#pragma unroll 8
  for (int e = 0; e < D_; ++e) {
    float pp = ppb[e * P_ + p];
    float2 c = F.cws[wv][e];
    float x = pp + c.x;
    float ex = __builtin_amdgcn_exp2f(-2.4554248f * x);  // -1.702*log2e
    float r = __builtin_amdgcn_rcpf(1.0f + ex);
    acc = fmaf(x * r, c.y, acc);
  }
  float logit = acc + beff;
  float es = __builtin_amdgcn_exp2f(-1.4426950408889634f * logit);
  P.out[(long)(b * P_ + p) * T_ + t] = __builtin_amdgcn_rcpf(1.0f + es);
}

// ---- launch wrappers -------------------------------------------------------
__global__ __launch_bounds__(256) void prep_k(Params P) {
  __shared__ PrepSM ps; do_prep(ps, P, blockIdx.x);
}
__global__ __launch_bounds__(256) void qkv_k(Params P, int l) {
  __shared__ GemmSM g; do_qkv(g, P, l, blockIdx.x);
}
// attn(l=0) + pproj + weff riders (riders depend only on prep)
__global__ __launch_bounds__(256) void apw_k(Params P) {
  __shared__ union __align__(16) { AttnSM a; GemmSM g; } sm;
  int bid = blockIdx.x;
  if (bid < 256) do_attn(sm.a, P, bid);
  else if (bid < 2304) do_pproj(sm.g, P, bid - 256);
  else do_weff(sm.g, P, bid - 2304);
}
__global__ __launch_bounds__(256) void attn_k(Params P) {
  __shared__ AttnSM a; do_attn(a, P, blockIdx.x);
}
__global__ __launch_bounds__(256) void proj_k(Params P, int l) {
  __shared__ GemmSM g; do_proj(g, P, l, blockIdx.x);
}
__global__ __launch_bounds__(256) void ln_k(const float* __restrict__ s,
                                            float* __restrict__ xout,
                                            const float* __restrict__ g,
                                            const float* __restrict__ be) {
  int wv = threadIdx.x >> 6, lane = threadIdx.x & 63;
  int m = blockIdx.x * 4 + wv;
  float4 v = *(const float4*)(s + (long)m * D_ + lane * 4);
  float sum = v.x + v.y + v.z + v.w;
  float ss = v.x * v.x + v.y * v.y + v.z * v.z + v.w * v.w;
#pragma unroll
  for (int mk = 1; mk < 64; mk <<= 1) {
    sum += __shfl_xor(sum, mk);
    ss += __shfl_xor(ss, mk);
  }
  float mean = sum * (1.0f / D_);
  float inv = rsqrtf(ss * (1.0f / D_) - mean * mean + EPS_);
  float4 g4 = *(const float4*)(g + lane * 4);
  float4 b4 = *(const float4*)(be + lane * 4);
  float4 o;
  o.x = (v.x - mean) * inv * g4.x + b4.x;
  o.y = (v.y - mean) * inv * g4.y + b4.y;
  o.z = (v.z - mean) * inv * g4.z + b4.z;
  o.w = (v.w - mean) * inv * g4.w + b4.w;
  *(float4*)(xout + (long)m * D_ + lane * 4) = o;
}
__global__ __launch_bounds__(256) void w1_k(Params P, int l) {
  __shared__ GemmSM g; do_w1(g, P, l, blockIdx.x);
}
__global__ __launch_bounds__(256) void w2_k(Params P, int l) {
  __shared__ GemmSM g; do_w2(g, P, l, blockIdx.x);
}
__global__ __launch_bounds__(256) void cproj_k(Params P) {
  __shared__ CprojSM c; do_cproj(c, P, (blockIdx.x >> 3) * 32, (blockIdx.x & 7) * 32);
}
__global__ __launch_bounds__(256) void final_k(Params P) {
  __shared__ FinalSM f; do_final(f, P, blockIdx.x);
}

extern "C" void kernel_launch(void* const* d_in, const int* in_sizes, int n_in, void* d_out,
                              int out_size, void* d_ws, size_t ws_size, hipStream_t stream) {
  Params P;
  P.patches = (const float*)d_in[0];
  P.tokens = (const int*)d_in[1];
  P.tok_emb = (const float*)d_in[2];
  P.pos_emb = (const float*)d_in[3];
  P.qkv_w = (const float*)d_in[4];
  P.qkv_b = (const float*)d_in[5];
  P.out_w = (const float*)d_in[6];
  P.out_b = (const float*)d_in[7];
  P.ln1_s = (const float*)d_in[8];
  P.ln1_b = (const float*)d_in[9];
  P.w1 = (const float*)d_in[10];
  P.b1 = (const float*)d_in[11];
  P.w2 = (const float*)d_in[12];
  P.b2 = (const float*)d_in[13];
  P.ln2_s = (const float*)d_in[14];
  P.ln2_b = (const float*)d_in[15];
  P.fus_w1 = (const float*)d_in[16];
  P.fus_b1 = (const float*)d_in[17];
  P.fus_w2 = (const float*)d_in[18];
  P.fus_b2 = (const float*)d_in[19];
  P.cls_w = (const float*)d_in[20];
  P.cls_b = (const float*)d_in[21];
  P.out = (float*)d_out;

  const int MT = B_ * T_;  // 1280
  P.x = (float*)d_ws;                          // 1280*256
  P.qkvbuf = P.x + MT * D_;                    // 1280*768
  P.attbuf = P.qkvbuf + MT * 3 * D_;           // 1280*256
  P.s = P.attbuf + MT * D_;                    // 1280*256
  P.pprojT = P.s + MT * D_;                    // 32*256*256 [b][e][p]
  P.cw = P.pprojT + (long)B_ * D_ * P_;        // 1280*512 {cproj,weff}
  P.wb = (bf16*)(P.cw + MT * D_ * 2);          // bf16 fus_w1 arena
  P.w2Tb = P.wb + FUS_ELEMS;                   // 256*256
  P.patb = P.w2Tb + D_ * D_;                   // 32*256*384
  P.hb = P.patb + (long)B_ * P_ * DINO_;       // 1280*1024 bf16

  // 1. prep (788 blocks, single pass): embed->x, fus_w2 transpose,
  //    fus_w1->bf16, patches->bf16
  prep_k<<<PREP_UNITS, 256, 0, stream>>>(P);
  // 2. qkv(l=0), W staged from fp32
  qkv_k<<<960, 256, 0, stream>>>(P, 0);
  // 3. attn(l=0) + pproj + weff riders (fill idle CUs; tail shrinks to cproj)
  apw_k<<<2624, 256, 0, stream>>>(P);
  // 4. proj(l=0) + resid
  proj_k<<<320, 256, 0, stream>>>(P, 0);
  // 5. x = LN1(s)
  ln_k<<<320, 256, 0, stream>>>(P.s, P.x, P.ln1_s, P.ln1_b);
  // 6. hb = relu(x @ w1^T + b1)
  w1_k<<<1280, 256, 0, stream>>>(P, 0);
  // 7. s = hb @ w2^T + b2 + x
  w2_k<<<320, 256, 0, stream>>>(P, 0);
  // 8. x = LN2(s)
  ln_k<<<320, 256, 0, stream>>>(P.s, P.x, P.ln2_s, P.ln2_b);
  // 9-14. layer 1
  qkv_k<<<960, 256, 0, stream>>>(P, 1);
  attn_k<<<256, 256, 0, stream>>>(P);
  proj_k<<<320, 256, 0, stream>>>(P, 1);
  ln_k<<<320, 256, 0, stream>>>(P.s, P.x, P.ln1_s + D_, P.ln1_b + D_);
  w1_k<<<1280, 256, 0, stream>>>(P, 1);
  w2_k<<<320, 256, 0, stream>>>(P, 1);
  // 15. cproj: shifted LN2(l=1) folded -> cw even (+fus_b1)
  cproj_k<<<320, 256, 0, stream>>>(P);
  // 16. final
  final_k<<<1280, 256, 0, stream>>>(P);
}